// Round 17
// baseline (71.040 us; speedup 1.0000x reference)
//
#include <hip/hip_runtime.h>
#include <hip/hip_bf16.h>

#define NUM_CLASSES 6
#define NUM_SUBJECTS 16
#define NUM_PAIRS (NUM_CLASSES * NUM_SUBJECTS)   // 96
#define MARGIN 1.0f
#define EPS 1e-6f
#define INF_U 0xffffffffu

typedef float f32x4 __attribute__((ext_vector_type(4)));
typedef short s16x8 __attribute__((ext_vector_type(8)));

// ---------------- ws layout (bytes) ----------------
// 0xFF-memset region:
// [0)      u32   min1[96]        sentinel 0xFFFFFFFF
// [384)    u32   min2[96]        sentinel 0xFFFFFFFF
// [768)    u64   best[96]        sentinel ~0ull; packed (fkey(e2-2dot)<<32)|idx
// 0x00-memset region:
// [1536)   int   cntPos[96]
// [1920)   int   cntSbj[16]
// [1984)   int   done
// [2048)   u64   ancT[96*64]     bf16 anchors, linear [pair][256] (49152 B)

__device__ __forceinline__ unsigned int fkey(float f) {
    unsigned int b = __float_as_uint(f);
    return (b & 0x80000000u) ? ~b : (b | 0x80000000u);
}

__device__ __forceinline__ unsigned int pkbf(float x, float y) {
    unsigned short a = __builtin_bit_cast(unsigned short, __float2bfloat16(x));
    unsigned short b = __builtin_bit_cast(unsigned short, __float2bfloat16(y));
    return (unsigned int)a | ((unsigned int)b << 16);
}

// Fused: first-two-positive mining + counts + (last block) anchor gather.
// Lock-free two-min: o = atomicMin(min1, i); atomicMin(min2, max(o, i)).
__global__ __launch_bounds__(1024) void k_stats(const float4* __restrict__ emb4,
                                                const int* __restrict__ labels,
                                                const int* __restrict__ sbj,
                                                unsigned int* min1, unsigned int* min2,
                                                int* cntPos, int* cntSbj, int* done,
                                                unsigned long long* ancT, int B) {
    __shared__ unsigned int l1[NUM_PAIRS], l2[NUM_PAIRS];
    __shared__ int lcp[NUM_PAIRS], lcs[NUM_SUBJECTS];
    __shared__ int lastDone;
    __shared__ unsigned int idxL[NUM_PAIRS];
    for (int t = threadIdx.x; t < NUM_PAIRS; t += blockDim.x) { l1[t] = INF_U; l2[t] = INF_U; lcp[t] = 0; }
    if (threadIdx.x < NUM_SUBJECTS) lcs[threadIdx.x] = 0;
    __syncthreads();
    for (int i = blockIdx.x * blockDim.x + threadIdx.x; i < B; i += gridDim.x * blockDim.x) {
        int s = sbj[i], c = labels[i];
        int p = s * NUM_CLASSES + c;
        unsigned int o = atomicMin(&l1[p], (unsigned int)i);
        atomicMin(&l2[p], max(o, (unsigned int)i));   // max(INF,i)=INF on first insert
        atomicAdd(&lcp[p], 1);
        atomicAdd(&lcs[s], 1);
    }
    __syncthreads();
    for (int t = threadIdx.x; t < NUM_PAIRS; t += blockDim.x) {
        unsigned int m1 = l1[t];
        if (m1 != INF_U) {
            unsigned int o = atomicMin(&min1[t], m1);
            atomicMin(&min2[t], max(o, m1));
            if (l2[t] != INF_U) atomicMin(&min2[t], l2[t]);
            atomicAdd(&cntPos[t], lcp[t]);
        }
    }
    if (threadIdx.x < NUM_SUBJECTS && lcs[threadIdx.x]) atomicAdd(&cntSbj[threadIdx.x], lcs[threadIdx.x]);
    __syncthreads();
    if (threadIdx.x == 0) {
        __threadfence();                              // one per block (128 total)
        lastDone = (atomicAdd(done, 1) == (int)gridDim.x - 1);
    }
    __syncthreads();
    if (!lastDone) return;

    // ---- last block: gather 96 anchor rows -> bf16 ancT ----
    if (threadIdx.x < NUM_PAIRS)
        idxL[threadIdx.x] = atomicMin(&min1[threadIdx.x], INF_U);  // coherent RMW read
    __syncthreads();
    for (int u = threadIdx.x; u < NUM_PAIRS * 64; u += blockDim.x) {
        int pr = u >> 6, l = u & 63;
        unsigned int idx = idxL[pr];
        if (idx >= (unsigned int)B) idx = 0;
        float4 v = emb4[(size_t)idx * 64 + l];
        ancT[pr * 64 + l] = (unsigned long long)pkbf(v.x, v.y)
                          | ((unsigned long long)pkbf(v.z, v.w) << 32);
    }
}

// MFMA mine (r14, unchanged): per block (512 thr, 8 waves), 64 samples x
// 96 pairs x K=256. B staged in quarter-K chunks (12 KB); LDS ~46 KB ->
// 3 blocks/CU = 24 waves/CU. Wave roles: rt = wv&3, ch = wv>>2, 3 accs;
// ch==0 waves also accumulate G=A*A^T (diag = e2, bf16-precision key only).
// A/B XOR-swizzled (byte ^ ((row&7)<<4)). C layout (m89): col=lane&15,
// row=(lane>>4)*4+reg. Key = e2 - 2*S (|a|^2 is per-pair constant).
__global__ __launch_bounds__(512, 6) void k_mine(const float4* __restrict__ emb4,
                                                 const int* __restrict__ labels,
                                                 const int* __restrict__ sbj,
                                                 const unsigned long long* __restrict__ ancT,
                                                 unsigned long long* gbest, int B) {
    __shared__ __align__(16) char ldsA[64 * 512];    // 64 rows x 256 bf16 (32768 B)
    __shared__ __align__(16) char ldsB[96 * 128];    // 96 pairs x 64 bf16 quarter (12288 B)
    __shared__ float e2s[64];
    __shared__ int sbjT[64], lblT[64];
    __shared__ unsigned long long lbest[NUM_PAIRS];

    const int t = threadIdx.x;
    const int R0 = (int)blockIdx.x * 64;
    const int lane = t & 63;
    const int wv = t >> 6;                           // 0..7

    for (int u = t; u < NUM_PAIRS; u += blockDim.x) lbest[u] = ~0ull;

    // ---- stage A: 64 rows x 64 float4 = 4096 float4, 8 iters x 512 thr ----
#pragma unroll
    for (int it = 0; it < 8; ++it) {
        int fi = it * 512 + t;                       // float4 index in tile
        float4 v = emb4[(size_t)R0 * 64 + fi];
        int row = it * 8 + wv;                       // == fi >> 6
        unsigned long long u = (unsigned long long)pkbf(v.x, v.y)
                             | ((unsigned long long)pkbf(v.z, v.w) << 32);
        int off = (lane * 8) ^ ((row & 7) << 4);
        *(unsigned long long*)(ldsA + row * 512 + off) = u;
    }
    if (t < 64) { sbjT[t] = sbj[R0 + t]; lblT[t] = labels[R0 + t]; }

    const int rt = wv & 3;                           // row-tile 0..3
    const int ch = wv >> 2;                          // col half 0/1
    const int col = lane & 15;
    const int rloc = rt * 16 + col;                  // A-frag row
    const int asw = (col & 7) << 4;
    const int kgrp = (lane >> 4) << 4;               // 0,16,32,48 bytes

    f32x4 acc[3];
#pragma unroll
    for (int ct = 0; ct < 3; ++ct) acc[ct] = f32x4{0.f, 0.f, 0.f, 0.f};
    f32x4 aG = f32x4{0.f, 0.f, 0.f, 0.f};

#pragma unroll
    for (int kq = 0; kq < 4; ++kq) {                 // quarter-K chunks (K=64 each)
        if (kq > 0) __syncthreads();                 // done reading prev chunk
        // stage B quarter kq: 96 pairs x 8 ulonglong2 = 768 chunks
        {
            const ulonglong2* src = (const ulonglong2*)ancT;
            int u = t;
            if (u < 768) {
                int pair = u >> 3, w = u & 7;
                ulonglong2 val = src[pair * 32 + kq * 8 + w];
                *(ulonglong2*)(ldsB + pair * 128 + ((w * 16) ^ ((pair & 7) << 4))) = val;
            }
            u = t + 512;
            if (u < 768) {
                int pair = u >> 3, w = u & 7;
                ulonglong2 val = src[pair * 32 + kq * 8 + w];
                *(ulonglong2*)(ldsB + pair * 128 + ((w * 16) ^ ((pair & 7) << 4))) = val;
            }
        }
        __syncthreads();
#pragma unroll
        for (int ksl = 0; ksl < 2; ++ksl) {          // two 16x16x32 slices per quarter
            int kbB = ksl * 64 + kgrp;               // byte offset in 128 B B-row
            int kbA = kq * 128 + kbB;                // byte offset in 512 B A-row
            s16x8 a = *(const s16x8*)(ldsA + rloc * 512 + (kbA ^ asw));
            if (ch == 0)                             // G = A*A^T (e2 on diag)
                aG = __builtin_amdgcn_mfma_f32_16x16x32_bf16(a, a, aG, 0, 0, 0);
#pragma unroll
            for (int ct = 0; ct < 3; ++ct) {
                int p = (ch * 3 + ct) * 16 + col;
                s16x8 b = *(const s16x8*)(ldsB + p * 128 + (kbB ^ ((p & 7) << 4)));
                acc[ct] = __builtin_amdgcn_mfma_f32_16x16x32_bf16(a, b, acc[ct], 0, 0, 0);
            }
        }
    }
    // diag(G): row == col -> lane>>4 == col>>2, reg = col&3
    if (ch == 0 && (lane >> 4) == (col >> 2)) e2s[rt * 16 + col] = aG[col & 3];
    __syncthreads();

    // ---- epilogue: key = e2 - 2*S, predicated LDS atomicMin ----
    const int rb = rt * 16 + ((lane >> 4) << 2);     // this lane's 4 C rows
    float e2r[4]; int sr[4], lr[4];
#pragma unroll
    for (int r = 0; r < 4; ++r) { e2r[r] = e2s[rb + r]; sr[r] = sbjT[rb + r]; lr[r] = lblT[rb + r]; }
#pragma unroll
    for (int ct = 0; ct < 3; ++ct) {
        int p = (ch * 3 + ct) * 16 + col;
        int sp = p / NUM_CLASSES, cp = p - sp * NUM_CLASSES;
#pragma unroll
        for (int r = 0; r < 4; ++r) {
            if (sr[r] == sp && lr[r] != cp) {
                float key = e2r[r] - 2.0f * acc[ct][r];
                unsigned long long pk =
                    ((unsigned long long)fkey(key) << 32) | (unsigned int)(R0 + rb + r);
                atomicMin(&lbest[p], pk);
            }
        }
    }
    __syncthreads();
    for (int u = t; u < NUM_PAIRS; u += blockDim.x) {
        unsigned long long v = lbest[u];
        if (v != ~0ull) {
            unsigned long long cur = gbest[u];       // racy monotone filter
            if (v < cur) atomicMin(&gbest[u], v);
        }
    }
}

__global__ __launch_bounds__(1024) void k_finalize(const float4* __restrict__ emb4,
                                                   const unsigned int* __restrict__ min1,
                                                   const unsigned int* __restrict__ min2,
                                                   const int* __restrict__ cntPos,
                                                   const int* __restrict__ cntSbj,
                                                   const unsigned long long* __restrict__ best,
                                                   float* out, int B) {
    __shared__ float vals[NUM_PAIRS];
    __shared__ int vld[NUM_PAIRS];
    int wave = threadIdx.x >> 6;
    int lane = threadIdx.x & 63;
    for (int p = wave; p < NUM_PAIRS; p += (blockDim.x >> 6)) {
        int s = p / NUM_CLASSES;
        unsigned int ai = min1[p], pi = min2[p];
        int npos = cntPos[p];
        int nneg = cntSbj[s] - npos;
        unsigned long long bb = best[p];
        unsigned int ni = (unsigned int)(bb & 0xffffffffu);
        bool ok = (npos >= 2) && (nneg >= 1) && (bb != ~0ull);
        if (ai >= (unsigned int)B) ai = 0;
        if (pi >= (unsigned int)B) pi = 0;
        if (ni >= (unsigned int)B) ni = 0;
        float4 a = emb4[(size_t)ai * 64 + lane];
        float4 pp = emb4[(size_t)pi * 64 + lane];
        float4 nn = emb4[(size_t)ni * 64 + lane];
        float dap = 0.f, dan = 0.f, tt;
        tt = a.x - pp.x + EPS; dap += tt * tt;
        tt = a.y - pp.y + EPS; dap += tt * tt;
        tt = a.z - pp.z + EPS; dap += tt * tt;
        tt = a.w - pp.w + EPS; dap += tt * tt;
        tt = a.x - nn.x + EPS; dan += tt * tt;
        tt = a.y - nn.y + EPS; dan += tt * tt;
        tt = a.z - nn.z + EPS; dan += tt * tt;
        tt = a.w - nn.w + EPS; dan += tt * tt;
#pragma unroll
        for (int m = 32; m >= 1; m >>= 1) {
            dap += __shfl_xor(dap, m, 64);
            dan += __shfl_xor(dan, m, 64);
        }
        if (lane == 0) {
            float lv = sqrtf(dap) - sqrtf(dan) + MARGIN;
            vals[p] = ok ? fmaxf(lv, 0.f) : 0.f;
            vld[p] = ok ? 1 : 0;
        }
    }
    __syncthreads();
    if (threadIdx.x == 0) {
        float sum = 0.f;
        int cnt = 0;
        for (int p = 0; p < NUM_PAIRS; ++p) { sum += vals[p]; cnt += vld[p]; }
        out[0] = (cnt > 0) ? (sum / (float)cnt) : 0.f;
    }
}

extern "C" void kernel_launch(void* const* d_in, const int* in_sizes, int n_in,
                              void* d_out, int out_size, void* d_ws, size_t ws_size,
                              hipStream_t stream) {
    const float* emb = (const float*)d_in[0];
    const int* labels = (const int*)d_in[1];
    const int* sbj = (const int*)d_in[2];
    float* out = (float*)d_out;
    const int B = in_sizes[1];           // 131072
    const float4* emb4 = (const float4*)emb;

    char* ws = (char*)d_ws;
    unsigned int* min1 = (unsigned int*)(ws + 0);
    unsigned int* min2 = (unsigned int*)(ws + 384);
    unsigned long long* best = (unsigned long long*)(ws + 768);
    int* cntPos = (int*)(ws + 1536);
    int* cntSbj = (int*)(ws + 1920);
    int* done = (int*)(ws + 1984);
    unsigned long long* ancT = (unsigned long long*)(ws + 2048);

    // init via memset nodes: sentinels 0xFF (min1,min2,best), zeros (counts,done)
    hipMemsetAsync(ws, 0xFF, 1536, stream);
    hipMemsetAsync(ws + 1536, 0x00, 452, stream);

    k_stats<<<128, 1024, 0, stream>>>(emb4, labels, sbj, min1, min2,
                                      cntPos, cntSbj, done, ancT, B);

    k_mine<<<B / 64, 512, 0, stream>>>(emb4, labels, sbj, ancT, best, B);

    k_finalize<<<1, 1024, 0, stream>>>(emb4, min1, min2, cntPos, cntSbj, best, out, B);
}

// Round 19
// 64.998 us; speedup vs baseline: 1.0930x; 1.0930x over previous
//
#include <hip/hip_runtime.h>
#include <hip/hip_bf16.h>

#define NUM_CLASSES 6
#define NUM_SUBJECTS 16
#define NUM_PAIRS (NUM_CLASSES * NUM_SUBJECTS)   // 96
#define MARGIN 1.0f
#define EPS 1e-6f
#define INF_I 0x7fffffff

typedef float f32x4 __attribute__((ext_vector_type(4)));
typedef short s16x8 __attribute__((ext_vector_type(8)));

// ---------------- ws layout (bytes) ----------------
// [0)      int   min1[96]
// [384)    int   min2[96]
// [768)    int   cntPos[96]
// [1152)   int   cntSbj[16]
// [1216)   u64   best[96]        packed (sortable_f32(e2-2dot)<<32)|idx
// [2048)   u64   ancT[96*64]     bf16 anchors, linear [pair][256] (49152 B)

__device__ __forceinline__ unsigned int fkey(float f) {
    unsigned int b = __float_as_uint(f);
    return (b & 0x80000000u) ? ~b : (b | 0x80000000u);
}

__device__ __forceinline__ unsigned int pkbf(float x, float y) {
    unsigned short a = __builtin_bit_cast(unsigned short, __float2bfloat16(x));
    unsigned short b = __builtin_bit_cast(unsigned short, __float2bfloat16(y));
    return (unsigned int)a | ((unsigned int)b << 16);
}

__global__ void k_init(int* min1, int* min2, int* cntPos, int* cntSbj,
                       unsigned long long* best) {
    int t = threadIdx.x;
    if (t < NUM_PAIRS) {
        min1[t] = INF_I;
        min2[t] = INF_I;
        cntPos[t] = 0;
        best[t] = ~0ull;
    }
    if (t < NUM_SUBJECTS) cntSbj[t] = 0;
}

// Fused: first-two-positive mining + counts, single pass.
__global__ __launch_bounds__(1024) void k_stats(const int* __restrict__ labels,
                                                const int* __restrict__ sbj,
                                                int* min1, int* min2, int* cntPos,
                                                int* cntSbj, int B) {
    __shared__ int l1[NUM_PAIRS], l2[NUM_PAIRS], lcp[NUM_PAIRS], lcs[NUM_SUBJECTS];
    for (int t = threadIdx.x; t < NUM_PAIRS; t += blockDim.x) { l1[t] = INF_I; l2[t] = INF_I; lcp[t] = 0; }
    if (threadIdx.x < NUM_SUBJECTS) lcs[threadIdx.x] = 0;
    __syncthreads();
    for (int i = blockIdx.x * blockDim.x + threadIdx.x; i < B; i += gridDim.x * blockDim.x) {
        int s = sbj[i], c = labels[i];
        int p = s * NUM_CLASSES + c;
        int o = atomicMin(&l1[p], i);
        atomicMin(&l2[p], max(o, i));
        atomicAdd(&lcp[p], 1);
        atomicAdd(&lcs[s], 1);
    }
    __syncthreads();
    for (int t = threadIdx.x; t < NUM_PAIRS; t += blockDim.x) {
        int m1 = l1[t];
        if (m1 != INF_I) {
            int o = atomicMin(&min1[t], m1);
            atomicMin(&min2[t], max(o, m1));
            if (l2[t] != INF_I) atomicMin(&min2[t], l2[t]);
            atomicAdd(&cntPos[t], lcp[t]);
        }
    }
    if (threadIdx.x < NUM_SUBJECTS && lcs[threadIdx.x]) atomicAdd(&cntSbj[threadIdx.x], lcs[threadIdx.x]);
}

// Gather 96 anchor rows, convert to bf16, store linear [pair][256] as u64x64.
__global__ void k_gather(const float4* __restrict__ emb4, const int* __restrict__ min1,
                         unsigned long long* ancT, int B) {
    int pr = blockIdx.x;         // 0..95
    int l = threadIdx.x;         // 0..63
    int idx = min1[pr];
    if (idx < 0 || idx >= B) idx = 0;
    float4 v = emb4[(size_t)idx * 64 + l];
    unsigned long long u = (unsigned long long)pkbf(v.x, v.y)
                         | ((unsigned long long)pkbf(v.z, v.w) << 32);
    ancT[pr * 64 + l] = u;
}

// MFMA mine (r14, best verified): per block (512 thr, 8 waves), 64 samples x
// 96 pairs x K=256. B staged in quarter-K chunks (12 KB); LDS ~46 KB ->
// 3 blocks/CU = 24 waves/CU. Wave roles: rt = wv&3, ch = wv>>2, 3 accs;
// ch==0 waves also accumulate G=A*A^T (diag = e2, bf16-precision key only).
// A/B XOR-swizzled (byte ^ ((row&7)<<4)). C layout (m89): col=lane&15,
// row=(lane>>4)*4+reg. Key = e2 - 2*S (|a|^2 is per-pair constant).
__global__ __launch_bounds__(512, 6) void k_mine(const float4* __restrict__ emb4,
                                                 const int* __restrict__ labels,
                                                 const int* __restrict__ sbj,
                                                 const unsigned long long* __restrict__ ancT,
                                                 unsigned long long* gbest, int B) {
    __shared__ __align__(16) char ldsA[64 * 512];    // 64 rows x 256 bf16 (32768 B)
    __shared__ __align__(16) char ldsB[96 * 128];    // 96 pairs x 64 bf16 quarter (12288 B)
    __shared__ float e2s[64];
    __shared__ int sbjT[64], lblT[64];
    __shared__ unsigned long long lbest[NUM_PAIRS];

    const int t = threadIdx.x;
    const int R0 = (int)blockIdx.x * 64;
    const int lane = t & 63;
    const int wv = t >> 6;                           // 0..7

    for (int u = t; u < NUM_PAIRS; u += blockDim.x) lbest[u] = ~0ull;

    // ---- stage A: 64 rows x 64 float4 = 4096 float4, 8 iters x 512 thr ----
#pragma unroll
    for (int it = 0; it < 8; ++it) {
        int fi = it * 512 + t;                       // float4 index in tile
        float4 v = emb4[(size_t)R0 * 64 + fi];
        int row = it * 8 + wv;                       // == fi >> 6
        unsigned long long u = (unsigned long long)pkbf(v.x, v.y)
                             | ((unsigned long long)pkbf(v.z, v.w) << 32);
        int off = (lane * 8) ^ ((row & 7) << 4);
        *(unsigned long long*)(ldsA + row * 512 + off) = u;
    }
    if (t < 64) { sbjT[t] = sbj[R0 + t]; lblT[t] = labels[R0 + t]; }

    const int rt = wv & 3;                           // row-tile 0..3
    const int ch = wv >> 2;                          // col half 0/1
    const int col = lane & 15;
    const int rloc = rt * 16 + col;                  // A-frag row
    const int asw = (col & 7) << 4;
    const int kgrp = (lane >> 4) << 4;               // 0,16,32,48 bytes

    f32x4 acc[3];
#pragma unroll
    for (int ct = 0; ct < 3; ++ct) acc[ct] = f32x4{0.f, 0.f, 0.f, 0.f};
    f32x4 aG = f32x4{0.f, 0.f, 0.f, 0.f};

#pragma unroll
    for (int kq = 0; kq < 4; ++kq) {                 // quarter-K chunks (K=64 each)
        if (kq > 0) __syncthreads();                 // done reading prev chunk
        // stage B quarter kq: 96 pairs x 8 ulonglong2 = 768 chunks
        {
            const ulonglong2* src = (const ulonglong2*)ancT;
            int u = t;
            if (u < 768) {
                int pair = u >> 3, w = u & 7;
                ulonglong2 val = src[pair * 32 + kq * 8 + w];
                *(ulonglong2*)(ldsB + pair * 128 + ((w * 16) ^ ((pair & 7) << 4))) = val;
            }
            u = t + 512;
            if (u < 768) {
                int pair = u >> 3, w = u & 7;
                ulonglong2 val = src[pair * 32 + kq * 8 + w];
                *(ulonglong2*)(ldsB + pair * 128 + ((w * 16) ^ ((pair & 7) << 4))) = val;
            }
        }
        __syncthreads();
#pragma unroll
        for (int ksl = 0; ksl < 2; ++ksl) {          // two 16x16x32 slices per quarter
            int kbB = ksl * 64 + kgrp;               // byte offset in 128 B B-row
            int kbA = kq * 128 + kbB;                // byte offset in 512 B A-row
            s16x8 a = *(const s16x8*)(ldsA + rloc * 512 + (kbA ^ asw));
            if (ch == 0)                             // G = A*A^T (e2 on diag)
                aG = __builtin_amdgcn_mfma_f32_16x16x32_bf16(a, a, aG, 0, 0, 0);
#pragma unroll
            for (int ct = 0; ct < 3; ++ct) {
                int p = (ch * 3 + ct) * 16 + col;
                s16x8 b = *(const s16x8*)(ldsB + p * 128 + (kbB ^ ((p & 7) << 4)));
                acc[ct] = __builtin_amdgcn_mfma_f32_16x16x32_bf16(a, b, acc[ct], 0, 0, 0);
            }
        }
    }
    // diag(G): row == col -> lane>>4 == col>>2, reg = col&3
    if (ch == 0 && (lane >> 4) == (col >> 2)) e2s[rt * 16 + col] = aG[col & 3];
    __syncthreads();

    // ---- epilogue: key = e2 - 2*S, predicated LDS atomicMin ----
    const int rb = rt * 16 + ((lane >> 4) << 2);     // this lane's 4 C rows
    float e2r[4]; int sr[4], lr[4];
#pragma unroll
    for (int r = 0; r < 4; ++r) { e2r[r] = e2s[rb + r]; sr[r] = sbjT[rb + r]; lr[r] = lblT[rb + r]; }
#pragma unroll
    for (int ct = 0; ct < 3; ++ct) {
        int p = (ch * 3 + ct) * 16 + col;
        int sp = p / NUM_CLASSES, cp = p - sp * NUM_CLASSES;
#pragma unroll
        for (int r = 0; r < 4; ++r) {
            if (sr[r] == sp && lr[r] != cp) {
                float key = e2r[r] - 2.0f * acc[ct][r];
                unsigned long long pk =
                    ((unsigned long long)fkey(key) << 32) | (unsigned int)(R0 + rb + r);
                atomicMin(&lbest[p], pk);
            }
        }
    }
    __syncthreads();
    for (int u = t; u < NUM_PAIRS; u += blockDim.x) {
        unsigned long long v = lbest[u];
        if (v != ~0ull) {
            unsigned long long cur = gbest[u];       // racy monotone filter
            if (v < cur) atomicMin(&gbest[u], v);
        }
    }
}

__global__ __launch_bounds__(1024) void k_finalize(const float4* __restrict__ emb4,
                                                   const int* __restrict__ min1,
                                                   const int* __restrict__ min2,
                                                   const int* __restrict__ cntPos,
                                                   const int* __restrict__ cntSbj,
                                                   const unsigned long long* __restrict__ best,
                                                   float* out, int B) {
    __shared__ float vals[NUM_PAIRS];
    __shared__ int vld[NUM_PAIRS];
    int wave = threadIdx.x >> 6;
    int lane = threadIdx.x & 63;
    for (int p = wave; p < NUM_PAIRS; p += (blockDim.x >> 6)) {
        int s = p / NUM_CLASSES;
        int ai = min1[p], pi = min2[p];
        int npos = cntPos[p];
        int nneg = cntSbj[s] - npos;
        unsigned long long bb = best[p];
        int ni = (int)(bb & 0xffffffffu);
        bool ok = (npos >= 2) && (nneg >= 1) && (bb != ~0ull);
        if (ai < 0 || ai >= B) ai = 0;
        if (pi < 0 || pi >= B) pi = 0;
        if (ni < 0 || ni >= B) ni = 0;
        float4 a = emb4[(size_t)ai * 64 + lane];
        float4 pp = emb4[(size_t)pi * 64 + lane];
        float4 nn = emb4[(size_t)ni * 64 + lane];
        float dap = 0.f, dan = 0.f, tt;
        tt = a.x - pp.x + EPS; dap += tt * tt;
        tt = a.y - pp.y + EPS; dap += tt * tt;
        tt = a.z - pp.z + EPS; dap += tt * tt;
        tt = a.w - pp.w + EPS; dap += tt * tt;
        tt = a.x - nn.x + EPS; dan += tt * tt;
        tt = a.y - nn.y + EPS; dan += tt * tt;
        tt = a.z - nn.z + EPS; dan += tt * tt;
        tt = a.w - nn.w + EPS; dan += tt * tt;
#pragma unroll
        for (int m = 32; m >= 1; m >>= 1) {
            dap += __shfl_xor(dap, m, 64);
            dan += __shfl_xor(dan, m, 64);
        }
        if (lane == 0) {
            float lv = sqrtf(dap) - sqrtf(dan) + MARGIN;
            vals[p] = ok ? fmaxf(lv, 0.f) : 0.f;
            vld[p] = ok ? 1 : 0;
        }
    }
    __syncthreads();
    if (threadIdx.x == 0) {
        float sum = 0.f;
        int cnt = 0;
        for (int p = 0; p < NUM_PAIRS; ++p) { sum += vals[p]; cnt += vld[p]; }
        out[0] = (cnt > 0) ? (sum / (float)cnt) : 0.f;
    }
}

extern "C" void kernel_launch(void* const* d_in, const int* in_sizes, int n_in,
                              void* d_out, int out_size, void* d_ws, size_t ws_size,
                              hipStream_t stream) {
    const float* emb = (const float*)d_in[0];
    const int* labels = (const int*)d_in[1];
    const int* sbj = (const int*)d_in[2];
    float* out = (float*)d_out;
    const int B = in_sizes[1];           // 131072
    const float4* emb4 = (const float4*)emb;

    char* ws = (char*)d_ws;
    int* min1 = (int*)(ws + 0);
    int* min2 = (int*)(ws + 384);
    int* cntPos = (int*)(ws + 768);
    int* cntSbj = (int*)(ws + 1152);
    unsigned long long* best = (unsigned long long*)(ws + 1216);
    unsigned long long* ancT = (unsigned long long*)(ws + 2048);

    k_init<<<1, 128, 0, stream>>>(min1, min2, cntPos, cntSbj, best);

    k_stats<<<128, 1024, 0, stream>>>(labels, sbj, min1, min2, cntPos, cntSbj, B);

    k_gather<<<NUM_PAIRS, 64, 0, stream>>>(emb4, min1, ancT, B);

    k_mine<<<B / 64, 512, 0, stream>>>(emb4, labels, sbj, ancT, best, B);

    k_finalize<<<1, 1024, 0, stream>>>(emb4, min1, min2, cntPos, cntSbj, best, out, B);
}